// Round 6
// baseline (90.005 us; speedup 1.0000x reference)
//
#include <hip/hip_runtime.h>

// CostVolume: out[b,c,d,h,w] = left[b,c,h,w] * right[b,c,h,w-d] (w>=d else 0),
// clipped to +-1000. B=1, C=32, H=160, W=320, D=64. Output 419.4 MB f32.
//
// R5 structure: block = (c,d); each block writes its WHOLE 204,800 B output
// slice sequentially (4 KB per pass, forward-moving front) to maximize DRAM
// page locality — fill kernel shows 6.9 TB/s with this pattern vs our 5.1.
//  - grid 2048 = 256 CU x 8 resident blocks (LDS 12 KB, launch_bounds(256,8))
//  - XCD-bijective swizzle: each XCD owns 4 channels -> 1.6 MB inputs L2-fit
//  - right rows staged in LDS (8-row chunks, 16-f4 zero pad per row):
//    aligned ds_read_b128 at 16B lane stride (conflict-free), w<d reads give
//    exact 0 via pad, A/B element-select compile-time via template<d&3>
//  - left read straight from global (L2 hit, 64x reuse within XCD)

typedef float fx4 __attribute__((ext_vector_type(4)));

constexpr float CLAMPV = 1000.0f;
constexpr int C  = 32;
constexpr int H  = 160;
constexpr int W  = 320;
constexpr int W4 = 80;             // f4 per row
constexpr int CH = 8;              // h rows per LDS chunk
constexpr int PAD = 16;            // f4 zero-pad per row (covers d <= 64)
constexpr int RS  = PAD + W4;      // padded row stride in f4 (96)
constexpr int BLOCK  = 256;
constexpr int NCHUNK = H / CH;     // 20
constexpr int CF4    = CH * W4;    // 640 f4 per chunk

__device__ __forceinline__ fx4 clamp4(fx4 l, fx4 r) {
    fx4 o;
    o.x = fminf(fmaxf(l.x * r.x, -CLAMPV), CLAMPV);
    o.y = fminf(fmaxf(l.y * r.y, -CLAMPV), CLAMPV);
    o.z = fminf(fmaxf(l.z * r.z, -CLAMPV), CLAMPV);
    o.w = fminf(fmaxf(l.w * r.w, -CLAMPV), CLAMPV);
    return o;
}

// S = d & 3. Window start = 4*w4 - d = 4*(w4-dq) - S; for S>0 the start falls
// at element O = 4-S of f4 qa = w4-dq-1. Select is compile-time renaming.
template<int S>
__device__ __forceinline__ void run(const float* __restrict__ lbase,
                                    const float* __restrict__ rbase,
                                    float* __restrict__ obase,
                                    fx4* __restrict__ sR,
                                    const int t, const int dq) {
    for (int ck = 0; ck < NCHUNK; ++ck) {
        const float* rrow = rbase + ck * CH * W;
        if (t < CH * PAD) {                   // zero pads (8 rows x 16 f4)
            const int row = t >> 4, col = t & 15;
            fx4 z = {0.f, 0.f, 0.f, 0.f};
            sR[row * RS + col] = z;
        }
        #pragma unroll
        for (int i = t; i < CF4; i += BLOCK) {  // stage right chunk
            const int row = i / W4, col = i - row * W4;
            sR[row * RS + PAD + col] =
                reinterpret_cast<const fx4*>(rrow + row * W)[col];
        }
        __syncthreads();

        const float* lrow = lbase + ck * CH * W;
        float*       orow = obase + ck * CH * W;
        #pragma unroll
        for (int i = t; i < CF4; i += BLOCK) {
            const int row = i / W4, w4 = i - row * W4;
            const fx4 l = reinterpret_cast<const fx4*>(lrow + row * W)[w4];
            const fx4* Ab = sR + row * RS + PAD;   // negative q -> zero pad
            const int qa = w4 - dq - (S ? 1 : 0);
            const fx4 A = Ab[qa];
            fx4 r;
            if constexpr (S == 0) {
                r = A;
            } else {
                const fx4 B = Ab[qa + 1];
                if constexpr (S == 1)      { fx4 v = {A.w, B.x, B.y, B.z}; r = v; }
                else if constexpr (S == 2) { fx4 v = {A.z, A.w, B.x, B.y}; r = v; }
                else                       { fx4 v = {A.y, A.z, A.w, B.x}; r = v; }
            }
            const fx4 o = clamp4(l, r);
            __builtin_nontemporal_store(o,
                reinterpret_cast<fx4*>(orow + row * W + 4 * w4));
        }
        __syncthreads();
    }
}

__global__ __launch_bounds__(BLOCK, 8) void costvol_kernel(
    const float* __restrict__ left,
    const float* __restrict__ right,
    float* __restrict__ out,
    int D)
{
    __shared__ fx4 sR[CH * RS];               // 12 KB

    // XCD-bijective swizzle: XCD x owns logical blocks [x*nwg/8,(x+1)*nwg/8)
    // => 4 channels per XCD => inputs L2-resident.
    int b = blockIdx.x;
    const int nwg = gridDim.x;
    if ((nwg & 7) == 0) {
        const int cpx = nwg >> 3;
        b = (b & 7) * cpx + (b >> 3);
    }

    const int c = b / D;
    const int d = b - c * D;
    const int t = threadIdx.x;

    const float* lbase = left  + (size_t)c * H * W;
    const float* rbase = right + (size_t)c * H * W;
    float*       obase = out   + (size_t)b * H * W;   // b = c*D + d

    const int dq = d >> 2;
    switch (d & 3) {
        case 0: run<0>(lbase, rbase, obase, sR, t, dq); break;
        case 1: run<1>(lbase, rbase, obase, sR, t, dq); break;
        case 2: run<2>(lbase, rbase, obase, sR, t, dq); break;
        default: run<3>(lbase, rbase, obase, sR, t, dq); break;
    }
}

extern "C" void kernel_launch(void* const* d_in, const int* in_sizes, int n_in,
                              void* d_out, int out_size, void* d_ws, size_t ws_size,
                              hipStream_t stream) {
    const float* left  = (const float*)d_in[0];
    const float* right = (const float*)d_in[1];
    float* out = (float*)d_out;

    const int D = out_size / in_sizes[0];   // 64 with the fixed setup

    dim3 grid(C * D, 1, 1);                 // 2048 blocks, one per (c,d)
    dim3 block(BLOCK, 1, 1);
    costvol_kernel<<<grid, block, 0, stream>>>(left, right, out, D);
}

// Round 7
// 87.902 us; speedup vs baseline: 1.0239x; 1.0239x over previous
//
#include <hip/hip_runtime.h>

// CostVolume: out[b,c,d,h,w] = left[b,c,h,w] * right[b,c,h,w-d] if w>=d else 0,
// clipped to +-1000. B=1, C=32, H=160, W=320, D=64 (runtime, from out_size).
// Output f32 = 419.4 MB -> streaming-write-bound. Inputs 13.1 MB total.
//
// R6 = R2 (best: 83.6 us) with ONE change: plain stores instead of
// __builtin_nontemporal_store. Single-variable ablation: the 6.9 TB/s fill
// kernel uses plain stores; nt's evict-first hint may defeat TCC write
// combining of the streaming output. Everything else byte-identical to R2:
// one block per (c,h) row pair, rows staged in LDS once, 1 barrier total,
// 20 f4 outputs/thread with guarded scalar right reads.

constexpr float CLAMPV = 1000.0f;
constexpr int C  = 32;
constexpr int H  = 160;
constexpr int W  = 320;
constexpr int W4 = W / 4;          // 80 float4 per row
constexpr int BLOCK = 256;

typedef float fx4 __attribute__((ext_vector_type(4)));

__global__ __launch_bounds__(BLOCK) void costvol_kernel(
    const float* __restrict__ left,
    const float* __restrict__ right,
    float* __restrict__ out,
    int D)
{
    const int ch = blockIdx.x;         // c*H + h
    const int c  = ch / H;             // compile-time divisor -> magic mul
    const int h  = ch - c * H;

    __shared__ float sL[W];
    __shared__ float sR[W];

    const float* lrow = left  + (size_t)ch * W;
    const float* rrow = right + (size_t)ch * W;

    const int t = threadIdx.x;
    if (t < W4) {
        reinterpret_cast<fx4*>(sL)[t] =
            reinterpret_cast<const fx4*>(lrow)[t];
    } else if (t < 2 * W4) {
        reinterpret_cast<fx4*>(sR)[t - W4] =
            reinterpret_cast<const fx4*>(rrow)[t - W4];
    }
    __syncthreads();

    // out[c][d][h][w] = ((c*D + d)*H + h)*W + w
    float* obase = out + ((size_t)c * D * H + h) * W;

    const int total = D * W4;          // 5120 float4 for this (c,h)
    for (int idx = t; idx < total; idx += BLOCK) {
        const int d  = idx / W4;       // compile-time divisor
        const int w4 = idx - d * W4;
        const int w  = w4 * 4;

        const fx4 l = reinterpret_cast<const fx4*>(sL)[w4];

        const int i0 = w - d;
        const float r0 = (i0     >= 0) ? sR[i0]     : 0.0f;
        const float r1 = (i0 + 1 >= 0) ? sR[i0 + 1] : 0.0f;
        const float r2 = (i0 + 2 >= 0) ? sR[i0 + 2] : 0.0f;
        const float r3 = (i0 + 3 >= 0) ? sR[i0 + 3] : 0.0f;

        fx4 o;
        o.x = fminf(fmaxf(l.x * r0, -CLAMPV), CLAMPV);
        o.y = fminf(fmaxf(l.y * r1, -CLAMPV), CLAMPV);
        o.z = fminf(fmaxf(l.z * r2, -CLAMPV), CLAMPV);
        o.w = fminf(fmaxf(l.w * r3, -CLAMPV), CLAMPV);

        // R6 ablation: plain (cacheable) store, NOT nontemporal.
        *reinterpret_cast<fx4*>(obase + (size_t)d * H * W + w) = o;
    }
}

extern "C" void kernel_launch(void* const* d_in, const int* in_sizes, int n_in,
                              void* d_out, int out_size, void* d_ws, size_t ws_size,
                              hipStream_t stream) {
    const float* left  = (const float*)d_in[0];
    const float* right = (const float*)d_in[1];
    float* out = (float*)d_out;

    const int D = out_size / in_sizes[0];   // 64 with the fixed setup

    dim3 grid(C * H, 1, 1);                 // 5120 blocks, one per (c,h)
    dim3 block(BLOCK, 1, 1);
    costvol_kernel<<<grid, block, 0, stream>>>(left, right, out, D);
}